// Round 11
// baseline (269.464 us; speedup 1.0000x reference)
//
#include <hip/hip_runtime.h>
#include <hip/hip_bf16.h>

#define MM 127
#define CHUNK_U16 4096        // per (matrix, k-chunk): 512 slots * 8 u16 = 8 KB
#define MAT_U16   16384       // 4 chunks per matrix = 32 KB
#define ARR_U16   1048576     // 64 matrices = 2 MB per array (X, Y)
#define QS_STRIDE 136         // per-lane stream stride (dwords); 136%32=8 -> uniform banks
#define QS_DWORDS (64 * QS_STRIDE)   // 8704 dwords = 34,816 B

typedef __attribute__((ext_vector_type(8))) short short8;
typedef __attribute__((ext_vector_type(4))) float floatx4;

__device__ __forceinline__ unsigned int pack_bf16_rne(float a, float b) {
  float2 rr; rr.x = a; rr.y = b;
  __hip_bfloat162 hp = __float22bfloat162_rn(rr);
  unsigned int hu; __builtin_memcpy(&hu, &hp, 4);
  return hu;
}

// wave_shr:1 via DPP: lane l gets lane l-1's value; lane 0 gets 0 (bound_ctrl)
__device__ __forceinline__ float wave_shr1(float x) {
  return __int_as_float(__builtin_amdgcn_update_dpp(
      0, __float_as_int(x), 0x138, 0xf, 0xf, true));
}

// ---- prep: increments -> RNE bf16, stored as the fragment image ----
// Swizzle: slot (r, h) holds 8-elem group g = h ^ ((r>>1)&3).  Reader lane
// (quad q, row r) reads slot h = q ^ ((r>>1)&3) -> gets group q.
__global__ __launch_bounds__(256) void prep_kernel(
    const float* __restrict__ X, const float* __restrict__ Y,
    unsigned short* __restrict__ base, float* __restrict__ acc)
{
  if (blockIdx.x == 0 && threadIdx.x == 0) acc[0] = 0.f;
  const int bid = blockIdx.x;
  const int c = bid & 3;
  const int m = (bid >> 2) & 63;
  const int isY = bid >> 8;
  const float* src = (isY ? Y : X) + m * 128 * 128;
  unsigned short* dst = base + isY * ARR_U16 + m * MAT_U16 + c * CHUNK_U16;

  for (int s = threadIdx.x; s < 512; s += 256) {
    const int r = s >> 2;
    const int g = (s & 3) ^ ((r >> 1) & 3);
    uint4 hv = make_uint4(0, 0, 0, 0);
    if (r < MM) {
      const float* p = src + r * 128 + c * 32 + g * 8;
      float4 u0 = *reinterpret_cast<const float4*>(p);
      float4 u1 = *reinterpret_cast<const float4*>(p + 4);
      float4 v0 = *reinterpret_cast<const float4*>(p + 128);
      float4 v1 = *reinterpret_cast<const float4*>(p + 132);
      hv.x = pack_bf16_rne(v0.x - u0.x, v0.y - u0.y);
      hv.y = pack_bf16_rne(v0.z - u0.z, v0.w - u0.w);
      hv.z = pack_bf16_rne(v1.x - u1.x, v1.y - u1.y);
      hv.w = pack_bf16_rne(v1.z - u1.z, v1.w - u1.w);
    }
    *reinterpret_cast<uint4*>(dst + s * 8) = hv;
  }
}

// R11 STRUCTURE: producer-consumer overlap inside the block.
// 3 producer waves compute the 64 MFMA tiles in ANTI-DIAGONAL order
// (d = tr+tc = 0..14) with per-tile immediate epilogue (R8-verified scatter,
// R7-verified direct-global fragment loads); 1 consumer wave runs the PDE
// trailing one diag behind.  Dependency: group g reads t = 4g..4g+3; all
// writers of t <= 16d+15 lie on diags <= d -> after barrier d the consumer
// may process groups 4d..4d+3.  Concurrent writers (diag d+1) touch
// t >= 16d+16 -- disjoint from the consumer's reads.  15 raw s_barriers:
// producers drain ds_writes (lgkmcnt(0) + memory clobber) before each;
// consumer loads after a compiler fence.  All 4 waves live to the end ->
// steady ~16 engaged waves/CU (vs 16-then-4 lockstep, the R1-R10 wall).
__global__ __launch_bounds__(256, 4) void sig_pair_kernel(
    const unsigned short* __restrict__ base, float* __restrict__ acc)
{
  __shared__ unsigned int smw[QS_DWORDS];
  unsigned short* const sm = reinterpret_cast<unsigned short*>(smw);
  const int tid = threadIdx.x;
  const int bid = blockIdx.x;

  // ---- decode block -> (gram type, a, b, weight) ----
  float w;
  int a, b, srcA, srcB;
  if (bid < 4160) {
    int p = bid;
    srcA = 0;
    if (p >= 2080) { p -= 2080; srcA = 1; }
    srcB = srcA;
    int ia = (int)((sqrtf(8.0f * (float)p + 1.0f) - 1.0f) * 0.5f);
    while ((ia + 1) * (ia + 2) / 2 <= p) ia++;
    while (ia * (ia + 1) / 2 > p) ia--;
    int ib = p - ia * (ia + 1) / 2;
    a = ia; b = ib;
    w = (a == b ? 1.0f : 2.0f) / 4096.0f;
  } else {
    int p = bid - 4160;
    a = p >> 6; b = p & 63;
    srcA = 0; srcB = 1;
    w = -2.0f / 4096.0f;
  }
  const unsigned short* Am = base + srcA * ARR_U16 + a * MAT_U16;
  const unsigned short* Bm = base + srcB * ARR_U16 + b * MAT_U16;

  const int wid = tid >> 6, lane = tid & 63;
  const int lrow = lane & 15, quad = lane >> 4;

  // ---- zero-fill the stream image (zeros = m-1 == -1 borders) ----
  {
    uint4 z = make_uint4(0u, 0u, 0u, 0u);
    uint4* smw4 = reinterpret_cast<uint4*>(smw);
    for (int i = tid; i < QS_DWORDS / 4; i += 256) smw4[i] = z;
  }
  __syncthreads();   // zero-fill visible before any epilogue write

  // consumer wave rotated across SIMDs per resident-generation
  const int cw = (bid >> 8) & 3;
  const bool isCons = (wid == cw);
  const int p = (wid < cw) ? wid : wid - 1;   // producer index 0..2

  // ---- consumer state (live across the d-loop) ----
  const int shift = 4 * (lane >> 1) + 4 * (lane & 1) - 4;
  const unsigned int lbase = lane * QS_STRIDE;
  float curE = 1.f, curO = 1.f;
  float npE = (lane == 0) ? 0.f : 1.f, npO = 1.f;

  auto loadg = [&](int g) -> uint4 {
    int pb = 4 * g - shift;
    pb = pb < 0 ? 132 : (pb > 128 ? 128 : pb);   // pre-band -> zero pad
    return *reinterpret_cast<const uint4*>(&smw[lbase + pb]);
  };
  auto estep = [&](unsigned int u) {
    float mE = __uint_as_float(u << 16) - 1.0f;
    float mO = __uint_as_float(u & 0xFFFF0000u) - 1.0f;
    float ncE = wave_shr1(curO);
    float ncO = curE;
    float vE = (curE + npE * mE) + ncE;
    float vO = (curO + npO * mO) + ncO;
    npE = ncE; npO = ncO;
    curE = vE; curO = vO;
  };
  auto do4 = [&](uint4 cur) {
    estep(cur.x); estep(cur.y); estep(cur.z); estep(cur.w);
  };

  for (int d = 0; d < 15; ++d) {
    if (!isCons) {
      // tiles on anti-diag d: (tr, d-tr), tr in [max(0,d-7), min(7,d)]
      const int tlo = (d > 7) ? (d - 7) : 0;
      const int thi = (d < 7) ? d : 7;
      int k = 0;
      for (int tr = tlo; tr <= thi; ++tr, ++k) {
        if ((k % 3) != p) continue;
        const int tc = d - tr;
        const int ra = tr * 16 + lrow;
        const int oa = ra * 32 + ((quad ^ ((ra >> 1) & 3)) * 8);
        const int rb = tc * 16 + lrow;
        const int ob = rb * 32 + ((quad ^ ((rb >> 1) & 3)) * 8);
        floatx4 a4 = (floatx4){0.f, 0.f, 0.f, 0.f};
#pragma unroll
        for (int c = 0; c < 4; ++c) {
          short8 ah = *reinterpret_cast<const short8*>(&Am[c * CHUNK_U16 + oa]);
          short8 bh = *reinterpret_cast<const short8*>(&Bm[c * CHUNK_U16 + ob]);
          a4 = __builtin_amdgcn_mfma_f32_16x16x32_bf16(ah, bh, a4, 0, 0, 0);
        }
        // per-tile epilogue (R8-verified): odd jm -> E (low u16) of lane
        // (jm+1)/2; even jm -> O (high u16) of lane jm/2.
        // phys = im + jm + 5 - 4*(lt>>1) - 4*(lt&1); e=3 valid iff im0 != 124.
        const int jm = tc * 16 + lrow;
        if (jm < MM) {
          const int im0 = tr * 16 + quad * 4;
          const int lt = (jm + 1) >> 1;
          const int half = (jm & 1) ? 0 : 1;
          const int phys0 = im0 + jm + 5 - 4 * (lt >> 1) - 4 * (lt & 1);
          unsigned short* pp = &sm[(lt * QS_STRIDE + phys0) * 2 + half];
          unsigned int u01 = pack_bf16_rne(a4[0], a4[1]);
          unsigned int u23 = pack_bf16_rne(a4[2], a4[3]);
          pp[0] = (unsigned short)u01;
          pp[2] = (unsigned short)(u01 >> 16);
          pp[4] = (unsigned short)u23;
          if (im0 + 3 < MM) pp[6] = (unsigned short)(u23 >> 16);
        }
      }
      // drain my ds_writes so they are LDS-visible at the barrier
      asm volatile("s_waitcnt lgkmcnt(0)" ::: "memory");
    }
    __builtin_amdgcn_s_barrier();        // raw: does NOT drain consumer state
    asm volatile("" ::: "memory");       // fence: no load hoisting above barrier
    if (isCons) {
      const int g0 = 4 * d;              // groups 4d..4d+3 (t = 16d..16d+15)
      uint4 Q0 = loadg(g0),     Q1 = loadg(g0 + 1);
      uint4 Q2 = loadg(g0 + 2), Q3 = loadg(g0 + 3);
      do4(Q0); do4(Q1); do4(Q2); do4(Q3);
    }
  }
  // tail: groups 60..63 (t = 240..253) -- all writers (diag <= 14) done
  if (isCons) {
    uint4 Q0 = loadg(60), Q1 = loadg(61), Q2 = loadg(62), Q3 = loadg(63);
    do4(Q0); do4(Q1); do4(Q2);
    estep(Q3.x); estep(Q3.y);            // t = 252, 253
    if (lane == 63) atomicAdd(acc, w * curO);   // col 127 = odd col of lane 63
  }
}

__global__ void finalize_kernel(const float* __restrict__ acc,
                                unsigned int* __restrict__ out) {
  float v = acc[0];
  __hip_bfloat16 bv = __float2bfloat16(v);
  unsigned short u;
  __builtin_memcpy(&u, &bv, sizeof(u));
  out[0] = ((unsigned int)u << 16) | (unsigned int)u;
}

extern "C" void kernel_launch(void* const* d_in, const int* in_sizes, int n_in,
                              void* d_out, int out_size, void* d_ws, size_t ws_size,
                              hipStream_t stream) {
  const float* X = (const float*)d_in[0];
  const float* Y = (const float*)d_in[1];
  float* acc = (float*)d_ws;                                     // 4 B @ 0
  unsigned short* base = (unsigned short*)((char*)d_ws + 1024);  // 4 MB arrays

  prep_kernel<<<512, 256, 0, stream>>>(X, Y, base, acc);
  sig_pair_kernel<<<8256, 256, 0, stream>>>(base, acc);
  finalize_kernel<<<1, 1, 0, stream>>>(acc, (unsigned int*)d_out);
}